// Round 7
// baseline (1696.791 us; speedup 1.0000x reference)
//
#include <hip/hip_runtime.h>
#include <math.h>

#define C        128
#define BLK      256
#define WPB      (BLK / 64)   // 4 waves per block
#define MAXSLOT  12           // 12 slots x 4 rows = 48 rows register-staged / segment

__device__ __forceinline__ float4 f4add(float4 a, float4 b) {
    float4 r; r.x = a.x + b.x; r.y = a.y + b.y; r.z = a.z + b.z; r.w = a.w + b.w; return r;
}
__device__ __forceinline__ float4 f4shfl_xor(float4 v, int m) {
    float4 r;
    r.x = __shfl_xor(v.x, m, 64);
    r.y = __shfl_xor(v.y, m, 64);
    r.z = __shfl_xor(v.z, m, 64);
    r.w = __shfl_xor(v.w, m, 64);
    return r;
}
__device__ __forceinline__ float fast_tanh(float v) {
    const float t = __expf(2.0f * v);
    return 1.0f - 2.0f / (t + 1.0f);
}
__device__ __forceinline__ float fast_sigmoid(float v) {
    return 1.0f / (1.0f + __expf(-v));
}
// RNE-pack two fp32 into one u32 of bf16s (a -> low16, b -> high16)
__device__ __forceinline__ uint32_t pack2(float a, float b) {
    uint32_t ua = __float_as_uint(a), ub = __float_as_uint(b);
    ua = (ua + 0x7FFFu + ((ua >> 16) & 1u)) >> 16;
    ub = (ub + 0x7FFFu + ((ub >> 16) & 1u)) & 0xFFFF0000u;
    return ua | ub;
}
__device__ __forceinline__ uint2 packf4(float4 v) {
    uint2 r; r.x = pack2(v.x, v.y); r.y = pack2(v.z, v.w); return r;
}
__device__ __forceinline__ float4 unpack4(uint2 p) {
    float4 v;
    v.x = __uint_as_float(p.x << 16);
    v.y = __uint_as_float(p.x & 0xFFFF0000u);
    v.z = __uint_as_float(p.y << 16);
    v.w = __uint_as_float(p.y & 0xFFFF0000u);
    return v;
}
// sum across the 16 lanes of this row-group; pure VALU (DPP row_ror tree)
__device__ __forceinline__ float row16_sum(float d) {
    d += __int_as_float(__builtin_amdgcn_update_dpp(0, __float_as_int(d), 0x128, 0xF, 0xF, true));
    d += __int_as_float(__builtin_amdgcn_update_dpp(0, __float_as_int(d), 0x124, 0xF, 0xF, true));
    d += __int_as_float(__builtin_amdgcn_update_dpp(0, __float_as_int(d), 0x122, 0xF, 0xF, true));
    d += __int_as_float(__builtin_amdgcn_update_dpp(0, __float_as_int(d), 0x121, 0xF, 0xF, true));
    return d;
}
__device__ __forceinline__ float dot8(float4 lo, float4 hi, float4 clo, float4 chi) {
    float a = lo.x * clo.x + lo.y * clo.y;
    float b = lo.z * clo.z + lo.w * clo.w;
    float c = hi.x * chi.x + hi.y * chi.y;
    float d = hi.z * chi.z + hi.w * chi.w;
    return (a + b) + (c + d);
}

extern "C" __global__ __launch_bounds__(BLK, 4)   // cap 128 VGPR -> 16 waves/CU; natural need ~115
void cba_bf16dpp_kernel(const float* __restrict__ x,
                        const float* __restrict__ W,
                        const int* __restrict__ batch,
                        float* __restrict__ out,
                        int N, int B, int totalWaves)
{
    // W as bf16 pairs: row k = 64 u32; column index rotated by (k>>5)*8 so the 4
    // row-groups (which read k-ranges 32 apart) land on disjoint LDS banks.
    __shared__ uint32_t sWb[C * 64];     // 32 KB
    __shared__ float4   sMean[WPB * 32]; // 2 KB: per-wave mean broadcast

    const int t    = threadIdx.x;
    const int lane = t & 63;
    const int wid  = t >> 6;       // wave in block 0..3
    const int rg   = lane >> 4;    // row-group 0..3 (also split-K quarter)
    const int c16  = lane & 15;    // owns channels c16*8 .. c16*8+7

    // ---- one-time: W -> bf16 -> LDS (swizzled) ----
    const float2* W2 = (const float2*)W;
    for (int p = t; p < C * 64; p += BLK) {
        const int k = p >> 6, j = p & 63;
        const float2 wv = W2[p];                       // W[k][2j], W[k][2j+1]
        sWb[(k << 6) | ((j + ((k >> 5) << 3)) & 63)] = pack2(wv.x, wv.y);
    }
    __syncthreads();

    const int gw = blockIdx.x * WPB + wid;

    // ---- chunk-contiguous segment assignment ----
    const int qn = B / totalWaves;
    const int r  = B % totalWaves;
    const int segStart = gw * qn + (gw < r ? gw : r);
    const int myCnt    = qn + (gw < r ? 1 : 0);        // ~12-13

    // ---- lane-parallel boundary search ----
    const int tl     = lane < myCnt ? lane : myCnt;
    const int target = segStart + tl;
    int lo_ = 0, hi_ = N;
    while (lo_ < hi_) {
        int mid = (lo_ + hi_) >> 1;
        if (batch[mid] < target) lo_ = mid + 1; else hi_ = mid;
    }
    const int bs = lo_;
    const float4* x4 = (const float4*)x;
    float4* mb = sMean + wid * 32;
    // per-lane constant swizzled column offset into a W row (rg constant per lane)
    const int co = ((c16 << 2) + (rg << 3)) & 63;

    for (int k = 0; k < myCnt; ++k) {
        const int b   = segStart + k;
        const int s   = __shfl(bs, k, 64);
        const int e   = __shfl(bs, k + 1, 64);
        const int cnt = e - s;

        // ======== stage 48 rows (bf16 in regs) + fused fp32 pass-1 sum; branchless ========
        uint2 rbA[MAXSLOT], rbB[MAXSLOT];
        float4 alo = make_float4(0.f,0.f,0.f,0.f), ahi = alo;
#pragma unroll
        for (int sl = 0; sl < MAXSLOT; ++sl) {
            const int row = s + 4 * sl + rg;
            const int rc  = row < N - 1 ? row : N - 1;           // always-valid address
            float4 vlo = x4[(size_t)rc * 32 + (c16 << 1)];
            float4 vhi = x4[(size_t)rc * 32 + (c16 << 1) + 1];
            const bool valid = row < e;
            vlo.x = valid ? vlo.x : 0.f; vlo.y = valid ? vlo.y : 0.f;
            vlo.z = valid ? vlo.z : 0.f; vlo.w = valid ? vlo.w : 0.f;
            vhi.x = valid ? vhi.x : 0.f; vhi.y = valid ? vhi.y : 0.f;
            vhi.z = valid ? vhi.z : 0.f; vhi.w = valid ? vhi.w : 0.f;
            rbA[sl] = packf4(vlo); rbB[sl] = packf4(vhi);
            alo = f4add(alo, vlo); ahi = f4add(ahi, vhi);
        }
        // rare tail rows > 48
        for (int i = s + 4 * MAXSLOT + rg; i < e; i += 4) {
            alo = f4add(alo, x4[(size_t)i * 32 + (c16 << 1)]);
            ahi = f4add(ahi, x4[(size_t)i * 32 + (c16 << 1) + 1]);
        }
        // cross-row-group reduce (per segment only)
        alo = f4add(alo, f4shfl_xor(alo, 16));
        alo = f4add(alo, f4shfl_xor(alo, 32));
        ahi = f4add(ahi, f4shfl_xor(ahi, 16));
        ahi = f4add(ahi, f4shfl_xor(ahi, 32));
        const float inv = 1.0f / (float)(cnt > 0 ? cnt : 1);
        if (lane < 16) {
            float4 mlo, mhi;
            mlo.x = alo.x*inv; mlo.y = alo.y*inv; mlo.z = alo.z*inv; mlo.w = alo.w*inv;
            mhi.x = ahi.x*inv; mhi.y = ahi.y*inv; mhi.z = ahi.z*inv; mhi.w = ahi.w*inv;
            mb[2 * c16]     = mlo;
            mb[2 * c16 + 1] = mhi;
        }
        // same-wave ds_write -> ds_read: compiler inserts lgkmcnt

        // ======== GEMM: c = tanh(mean @ W); group rg covers k in [32rg, 32rg+32) ========
        float4 plo = make_float4(0.f,0.f,0.f,0.f), phi = plo;
#pragma unroll
        for (int jq = 0; jq < 8; ++jq) {
            const float4 m4 = mb[(rg << 3) + jq];      // mean[k0..k0+3]
            const int kb = (rg << 5) + (jq << 2);
            const uint4 u0 = *(const uint4*)&sWb[((kb + 0) << 6) + co];
            const uint4 u1 = *(const uint4*)&sWb[((kb + 1) << 6) + co];
            const uint4 u2 = *(const uint4*)&sWb[((kb + 2) << 6) + co];
            const uint4 u3 = *(const uint4*)&sWb[((kb + 3) << 6) + co];
#define FMA8(mm, uu)                                                          \
            {                                                                 \
                plo.x = fmaf(mm, __uint_as_float((uu).x << 16),        plo.x);\
                plo.y = fmaf(mm, __uint_as_float((uu).x & 0xFFFF0000u),plo.y);\
                plo.z = fmaf(mm, __uint_as_float((uu).y << 16),        plo.z);\
                plo.w = fmaf(mm, __uint_as_float((uu).y & 0xFFFF0000u),plo.w);\
                phi.x = fmaf(mm, __uint_as_float((uu).z << 16),        phi.x);\
                phi.y = fmaf(mm, __uint_as_float((uu).z & 0xFFFF0000u),phi.y);\
                phi.z = fmaf(mm, __uint_as_float((uu).w << 16),        phi.z);\
                phi.w = fmaf(mm, __uint_as_float((uu).w & 0xFFFF0000u),phi.w);\
            }
            FMA8(m4.x, u0); FMA8(m4.y, u1); FMA8(m4.z, u2); FMA8(m4.w, u3);
#undef FMA8
        }
        // combine the 4 K-quarters
        plo = f4add(plo, f4shfl_xor(plo, 16));
        plo = f4add(plo, f4shfl_xor(plo, 32));
        phi = f4add(phi, f4shfl_xor(phi, 16));
        phi = f4add(phi, f4shfl_xor(phi, 32));
        float4 clo, chi;
        clo.x = fast_tanh(plo.x); clo.y = fast_tanh(plo.y);
        clo.z = fast_tanh(plo.z); clo.w = fast_tanh(plo.w);
        chi.x = fast_tanh(phi.x); chi.y = fast_tanh(phi.y);
        chi.z = fast_tanh(phi.z); chi.w = fast_tanh(phi.w);

        // ======== pass 2: gates + h from bf16 regs; DPP-only reduction ========
        float4 hlo = make_float4(0.f,0.f,0.f,0.f), hhi = hlo;
#pragma unroll
        for (int sl = 0; sl < MAXSLOT; ++sl) {
            const float4 vlo = unpack4(rbA[sl]);
            const float4 vhi = unpack4(rbB[sl]);
            float d = dot8(vlo, vhi, clo, chi);
            d = row16_sum(d);
            const float g = fast_sigmoid(d);           // masked rows: v=0 -> g*0
            hlo.x = fmaf(g, vlo.x, hlo.x); hlo.y = fmaf(g, vlo.y, hlo.y);
            hlo.z = fmaf(g, vlo.z, hlo.z); hlo.w = fmaf(g, vlo.w, hlo.w);
            hhi.x = fmaf(g, vhi.x, hhi.x); hhi.y = fmaf(g, vhi.y, hhi.y);
            hhi.z = fmaf(g, vhi.z, hhi.z); hhi.w = fmaf(g, vhi.w, hhi.w);
        }
        // tail rows > 48: re-read from global (L2-hot from pass 1)
        for (int i = s + 4 * MAXSLOT + rg; i < e; i += 4) {
            const float4 vlo = x4[(size_t)i * 32 + (c16 << 1)];
            const float4 vhi = x4[(size_t)i * 32 + (c16 << 1) + 1];
            float d = dot8(vlo, vhi, clo, chi);
            d = row16_sum(d);
            const float g = fast_sigmoid(d);
            hlo.x = fmaf(g, vlo.x, hlo.x); hlo.y = fmaf(g, vlo.y, hlo.y);
            hlo.z = fmaf(g, vlo.z, hlo.z); hlo.w = fmaf(g, vlo.w, hlo.w);
            hhi.x = fmaf(g, vhi.x, hhi.x); hhi.y = fmaf(g, vhi.y, hhi.y);
            hhi.z = fmaf(g, vhi.z, hhi.z); hhi.w = fmaf(g, vhi.w, hhi.w);
        }
        // cross-row-group combine + store
        hlo = f4add(hlo, f4shfl_xor(hlo, 16));
        hlo = f4add(hlo, f4shfl_xor(hlo, 32));
        hhi = f4add(hhi, f4shfl_xor(hhi, 16));
        hhi = f4add(hhi, f4shfl_xor(hhi, 32));
        if (lane < 16) {
            ((float4*)out)[(size_t)b * 32 + (c16 << 1)]     = hlo;
            ((float4*)out)[(size_t)b * 32 + (c16 << 1) + 1] = hhi;
        }
    }
}

extern "C" void kernel_launch(void* const* d_in, const int* in_sizes, int n_in,
                              void* d_out, int out_size, void* d_ws, size_t ws_size,
                              hipStream_t stream) {
    const float* x     = (const float*)d_in[0];
    const float* W     = (const float*)d_in[1];
    const int*   batch = (const int*)d_in[2];
    float*       out   = (float*)d_out;

    const int N = in_sizes[0] / C;   // 2,000,000
    const int B = out_size / C;      // 50,000

    const int grid       = 1024;                // 4 blocks/CU (34 KB LDS each), 16 waves/CU
    const int totalWaves = grid * WPB;          // 4096 waves, ~12 contiguous segments each
    hipLaunchKernelGGL(cba_bf16dpp_kernel, dim3(grid), dim3(BLK), 0, stream,
                       x, W, batch, out, N, B, totalWaves);
}

// Round 8
// 1623.107 us; speedup vs baseline: 1.0454x; 1.0454x over previous
//
#include <hip/hip_runtime.h>
#include <math.h>

#define C        128
#define BLK      512
#define WPB      (BLK / 64)      // 8 waves per block
#define MAXSLOT  12              // 12 slots x 4 rows = 48 rows staged per segment
#define NROW     (4 * MAXSLOT)   // 48
#define WSTRIDE  68              // u32 per padded bf16 row (64 data + 4 pad -> 272 B)

__device__ __forceinline__ float4 f4add(float4 a, float4 b) {
    float4 r; r.x = a.x + b.x; r.y = a.y + b.y; r.z = a.z + b.z; r.w = a.w + b.w; return r;
}
__device__ __forceinline__ float4 f4shfl_xor(float4 v, int m) {
    float4 r;
    r.x = __shfl_xor(v.x, m, 64);
    r.y = __shfl_xor(v.y, m, 64);
    r.z = __shfl_xor(v.z, m, 64);
    r.w = __shfl_xor(v.w, m, 64);
    return r;
}
__device__ __forceinline__ float fast_tanh(float v) {
    const float t = __expf(2.0f * v);
    return 1.0f - 2.0f / (t + 1.0f);
}
__device__ __forceinline__ float fast_sigmoid(float v) {
    return 1.0f / (1.0f + __expf(-v));
}
// RNE-pack two fp32 into one u32 of bf16 (a -> low16, b -> high16)
__device__ __forceinline__ uint32_t pack2(float a, float b) {
    uint32_t ua = __float_as_uint(a), ub = __float_as_uint(b);
    ua = (ua + 0x7FFFu + ((ua >> 16) & 1u)) >> 16;
    ub = (ub + 0x7FFFu + ((ub >> 16) & 1u)) & 0xFFFF0000u;
    return ua | ub;
}
__device__ __forceinline__ float4 unpack4(uint32_t a, uint32_t bql) {
    float4 v;
    v.x = __uint_as_float(a << 16);
    v.y = __uint_as_float(a & 0xFFFF0000u);
    v.z = __uint_as_float(bql << 16);
    v.w = __uint_as_float(bql & 0xFFFF0000u);
    return v;
}
// sum across the 16 lanes of this row-group; pure VALU (DPP row_ror tree)
__device__ __forceinline__ float row16_sum(float d) {
    d += __int_as_float(__builtin_amdgcn_update_dpp(0, __float_as_int(d), 0x128, 0xF, 0xF, true));
    d += __int_as_float(__builtin_amdgcn_update_dpp(0, __float_as_int(d), 0x124, 0xF, 0xF, true));
    d += __int_as_float(__builtin_amdgcn_update_dpp(0, __float_as_int(d), 0x122, 0xF, 0xF, true));
    d += __int_as_float(__builtin_amdgcn_update_dpp(0, __float_as_int(d), 0x121, 0xF, 0xF, true));
    return d;
}
__device__ __forceinline__ float dot8(float4 lo, float4 hi, float4 clo, float4 chi) {
    float a = lo.x * clo.x + lo.y * clo.y;
    float b = lo.z * clo.z + lo.w * clo.w;
    float c = hi.x * chi.x + hi.y * chi.y;
    float d = hi.z * chi.z + hi.w * chi.w;
    return (a + b) + (c + d);
}

extern "C" __global__ __launch_bounds__(BLK)   // 512 threads -> hard VGPR cap 256; natural ~200, no spill
void cba_lds_pipe_kernel(const float* __restrict__ x,
                         const float* __restrict__ W,
                         const int* __restrict__ batch,
                         float* __restrict__ out,
                         int N, int B, int totalWaves)
{
    __shared__ uint32_t sWb[C * WSTRIDE];              // 34816 B : bf16 W, padded rows
    __shared__ uint32_t sStage[WPB * NROW * WSTRIDE];  // 104448 B: per-wave staged segment (bf16)
    __shared__ float4   sMean[WPB * 32];               // 4096 B  : per-wave mean broadcast

    const int t    = threadIdx.x;
    const int lane = t & 63;
    const int wid  = t >> 6;       // wave in block 0..7
    const int rg   = lane >> 4;    // row-group / split-K quarter 0..3
    const int c16  = lane & 15;    // owns channels c16*8 .. c16*8+7

    // ---- one-time: W -> bf16 -> LDS (padded rows), only barrier in the kernel ----
    const float2* W2 = (const float2*)W;
    for (int p = t; p < C * 64; p += BLK) {
        const int k = p >> 6, j = p & 63;
        const float2 wv = W2[p];
        sWb[k * WSTRIDE + j] = pack2(wv.x, wv.y);
    }
    __syncthreads();

    const int gw = blockIdx.x * WPB + wid;

    // ---- chunk-contiguous segment assignment ----
    const int qn = B / totalWaves;
    const int r  = B % totalWaves;
    const int segStart = gw * qn + (gw < r ? gw : r);
    const int myCnt    = qn + (gw < r ? 1 : 0);        // <= 25

    // ---- lane-parallel boundary search: lane l -> start of segment segStart+min(l,myCnt) ----
    const int tl     = lane < myCnt ? lane : myCnt;
    const int target = segStart + tl;
    int lo_ = 0, hi_ = N;
    while (lo_ < hi_) {
        int mid = (lo_ + hi_) >> 1;
        if (batch[mid] < target) lo_ = mid + 1; else hi_ = mid;
    }
    const int bs = lo_;

    const float4* x4  = (const float4*)x;
    const int     Nm1 = N - 1;
    uint32_t* myStage = sStage + wid * (NROW * WSTRIDE);
    float4*   mb      = sMean + wid * 32;

    // in-flight prefetch registers: 24 float4 = 96 VGPR
    float4 vlo[MAXSLOT], vhi[MAXSLOT];

#define ISSUE(sseg)                                                    \
    {                                                                  \
        _Pragma("unroll")                                              \
        for (int sl = 0; sl < MAXSLOT; ++sl) {                         \
            const int row = (sseg) + 4 * sl + rg;                      \
            const int rc  = row < Nm1 ? row : Nm1;                     \
            vlo[sl] = x4[(size_t)rc * 32 + (c16 << 1)];                \
            vhi[sl] = x4[(size_t)rc * 32 + (c16 << 1) + 1];            \
        }                                                              \
    }

    int sCur = 0, eCur = 0;
    if (myCnt > 0) {
        sCur = __shfl(bs, 0, 64);
        eCur = __shfl(bs, 1, 64);
        ISSUE(sCur);                                    // prologue: segment 0 in flight
    }

    for (int k = 0; k < myCnt; ++k) {
        const int b   = segStart + k;
        const int s   = sCur;
        const int e   = eCur;
        const int cnt = e - s;

        // ======== consume prefetched rows: mask, fp32 sum, bf16-pack -> LDS stage ========
        float4 alo = make_float4(0.f,0.f,0.f,0.f), ahi = alo;
#pragma unroll
        for (int sl = 0; sl < MAXSLOT; ++sl) {
            const int  row   = s + 4 * sl + rg;
            const bool valid = row < e;
            float4 lo = vlo[sl], hi = vhi[sl];
            lo.x = valid ? lo.x : 0.f; lo.y = valid ? lo.y : 0.f;
            lo.z = valid ? lo.z : 0.f; lo.w = valid ? lo.w : 0.f;
            hi.x = valid ? hi.x : 0.f; hi.y = valid ? hi.y : 0.f;
            hi.z = valid ? hi.z : 0.f; hi.w = valid ? hi.w : 0.f;
            alo = f4add(alo, lo); ahi = f4add(ahi, hi);
            uint4 pk;
            pk.x = pack2(lo.x, lo.y); pk.y = pack2(lo.z, lo.w);
            pk.z = pack2(hi.x, hi.y); pk.w = pack2(hi.z, hi.w);
            *(uint4*)&myStage[(4 * sl + rg) * WSTRIDE + (c16 << 2)] = pk;
        }
        // tail rows > 48 (rare): sum synchronously
        for (int i = s + NROW + rg; i < e; i += 4) {
            alo = f4add(alo, x4[(size_t)i * 32 + (c16 << 1)]);
            ahi = f4add(ahi, x4[(size_t)i * 32 + (c16 << 1) + 1]);
        }

        // ======== prefetch segment k+1 NOW — flies during GEMM + pass 2 ========
        if (k + 1 < myCnt) {
            sCur = __shfl(bs, k + 1, 64);
            eCur = __shfl(bs, k + 2, 64);
            ISSUE(sCur);
        }

        // ======== mean (cross-row-group reduce, per segment only) ========
        alo = f4add(alo, f4shfl_xor(alo, 16));
        alo = f4add(alo, f4shfl_xor(alo, 32));
        ahi = f4add(ahi, f4shfl_xor(ahi, 16));
        ahi = f4add(ahi, f4shfl_xor(ahi, 32));
        const float inv = 1.0f / (float)(cnt > 0 ? cnt : 1);
        if (lane < 16) {
            float4 mlo, mhi;
            mlo.x = alo.x*inv; mlo.y = alo.y*inv; mlo.z = alo.z*inv; mlo.w = alo.w*inv;
            mhi.x = ahi.x*inv; mhi.y = ahi.y*inv; mhi.z = ahi.z*inv; mhi.w = ahi.w*inv;
            mb[2 * c16]     = mlo;
            mb[2 * c16 + 1] = mhi;
        }
        // same-wave ds_write->ds_read; compiler inserts lgkmcnt, no barrier needed

        // ======== GEMM: c = tanh(mean @ W); quarter rg covers k in [32rg, 32rg+32) ========
        float4 plo = make_float4(0.f,0.f,0.f,0.f), phi = plo;
#pragma unroll
        for (int jq = 0; jq < 8; ++jq) {
            const float4 m4 = mb[(rg << 3) + jq];        // broadcast within quarter
            const int kb = (rg << 5) + (jq << 2);
            const uint4 u0 = *(const uint4*)&sWb[(kb + 0) * WSTRIDE + (c16 << 2)];
            const uint4 u1 = *(const uint4*)&sWb[(kb + 1) * WSTRIDE + (c16 << 2)];
            const uint4 u2 = *(const uint4*)&sWb[(kb + 2) * WSTRIDE + (c16 << 2)];
            const uint4 u3 = *(const uint4*)&sWb[(kb + 3) * WSTRIDE + (c16 << 2)];
#define FMA8(mm, uu)                                                          \
            {                                                                 \
                plo.x = fmaf(mm, __uint_as_float((uu).x << 16),        plo.x);\
                plo.y = fmaf(mm, __uint_as_float((uu).x & 0xFFFF0000u),plo.y);\
                plo.z = fmaf(mm, __uint_as_float((uu).y << 16),        plo.z);\
                plo.w = fmaf(mm, __uint_as_float((uu).y & 0xFFFF0000u),plo.w);\
                phi.x = fmaf(mm, __uint_as_float((uu).z << 16),        phi.x);\
                phi.y = fmaf(mm, __uint_as_float((uu).z & 0xFFFF0000u),phi.y);\
                phi.z = fmaf(mm, __uint_as_float((uu).w << 16),        phi.z);\
                phi.w = fmaf(mm, __uint_as_float((uu).w & 0xFFFF0000u),phi.w);\
            }
            FMA8(m4.x, u0); FMA8(m4.y, u1); FMA8(m4.z, u2); FMA8(m4.w, u3);
#undef FMA8
        }
        plo = f4add(plo, f4shfl_xor(plo, 16));
        plo = f4add(plo, f4shfl_xor(plo, 32));
        phi = f4add(phi, f4shfl_xor(phi, 16));
        phi = f4add(phi, f4shfl_xor(phi, 32));
        float4 clo, chi;
        clo.x = fast_tanh(plo.x); clo.y = fast_tanh(plo.y);
        clo.z = fast_tanh(plo.z); clo.w = fast_tanh(plo.w);
        chi.x = fast_tanh(phi.x); chi.y = fast_tanh(phi.y);
        chi.z = fast_tanh(phi.z); chi.w = fast_tanh(phi.w);

        // ======== pass 2: gates + h from LDS stage; DPP-only row reduction ========
        float4 hlo = make_float4(0.f,0.f,0.f,0.f), hhi = hlo;
#pragma unroll
        for (int sl = 0; sl < MAXSLOT; ++sl) {
            const uint4 pk = *(const uint4*)&myStage[(4 * sl + rg) * WSTRIDE + (c16 << 2)];
            const float4 lo = unpack4(pk.x, pk.y);
            const float4 hi = unpack4(pk.z, pk.w);
            float d = dot8(lo, hi, clo, chi);
            d = row16_sum(d);
            const float g = fast_sigmoid(d);             // masked rows staged as 0 -> g*0
            hlo.x = fmaf(g, lo.x, hlo.x); hlo.y = fmaf(g, lo.y, hlo.y);
            hlo.z = fmaf(g, lo.z, hlo.z); hlo.w = fmaf(g, lo.w, hlo.w);
            hhi.x = fmaf(g, hi.x, hhi.x); hhi.y = fmaf(g, hi.y, hhi.y);
            hhi.z = fmaf(g, hi.z, hhi.z); hhi.w = fmaf(g, hi.w, hhi.w);
        }
        // tail rows > 48: re-read from global (L2-hot from the sum pass)
        for (int i = s + NROW + rg; i < e; i += 4) {
            const float4 lo = x4[(size_t)i * 32 + (c16 << 1)];
            const float4 hi = x4[(size_t)i * 32 + (c16 << 1) + 1];
            float d = dot8(lo, hi, clo, chi);
            d = row16_sum(d);
            const float g = fast_sigmoid(d);
            hlo.x = fmaf(g, lo.x, hlo.x); hlo.y = fmaf(g, lo.y, hlo.y);
            hlo.z = fmaf(g, lo.z, hlo.z); hlo.w = fmaf(g, lo.w, hlo.w);
            hhi.x = fmaf(g, hi.x, hhi.x); hhi.y = fmaf(g, hi.y, hhi.y);
            hhi.z = fmaf(g, hi.z, hhi.z); hhi.w = fmaf(g, hi.w, hhi.w);
        }
        hlo = f4add(hlo, f4shfl_xor(hlo, 16));
        hlo = f4add(hlo, f4shfl_xor(hlo, 32));
        hhi = f4add(hhi, f4shfl_xor(hhi, 16));
        hhi = f4add(hhi, f4shfl_xor(hhi, 32));
        if (lane < 16) {
            ((float4*)out)[(size_t)b * 32 + (c16 << 1)]     = hlo;
            ((float4*)out)[(size_t)b * 32 + (c16 << 1) + 1] = hhi;
        }
    }
#undef ISSUE
}

extern "C" void kernel_launch(void* const* d_in, const int* in_sizes, int n_in,
                              void* d_out, int out_size, void* d_ws, size_t ws_size,
                              hipStream_t stream) {
    const float* x     = (const float*)d_in[0];
    const float* W     = (const float*)d_in[1];
    const int*   batch = (const int*)d_in[2];
    float*       out   = (float*)d_out;

    const int N = in_sizes[0] / C;   // 2,000,000
    const int B = out_size / C;      // 50,000

    const int grid       = 256;                 // 1 block/CU (140 KB LDS), 8 waves/CU
    const int totalWaves = grid * WPB;          // 2048 waves, ~24 contiguous segments each
    hipLaunchKernelGGL(cba_lds_pipe_kernel, dim3(grid), dim3(BLK), 0, stream,
                       x, W, batch, out, N, B, totalWaves);
}

// Round 9
// 269.495 us; speedup vs baseline: 6.2962x; 6.0228x over previous
//
#include <hip/hip_runtime.h>
#include <math.h>

#define C        128
#define BLK      256
#define WPB      (BLK / 64)      // 4 waves per block
#define MAXSLOT  12              // 12 slots x 4 row-groups = 48 rows staged / segment
#define NROW     (4 * MAXSLOT)   // 48
#define WSTRIDE  68              // u32 per padded bf16 W row

__device__ __forceinline__ float4 f4add(float4 a, float4 b) {
    float4 r; r.x = a.x + b.x; r.y = a.y + b.y; r.z = a.z + b.z; r.w = a.w + b.w; return r;
}
__device__ __forceinline__ float4 f4shfl_xor(float4 v, int m) {
    float4 r;
    r.x = __shfl_xor(v.x, m, 64);
    r.y = __shfl_xor(v.y, m, 64);
    r.z = __shfl_xor(v.z, m, 64);
    r.w = __shfl_xor(v.w, m, 64);
    return r;
}
__device__ __forceinline__ float fast_tanh(float v) {
    const float t = __expf(2.0f * v);
    return 1.0f - 2.0f / (t + 1.0f);
}
__device__ __forceinline__ float fast_sigmoid(float v) {
    return 1.0f / (1.0f + __expf(-v));
}
// RNE-pack two fp32 into one u32 of bf16 (a -> low16, b -> high16)
__device__ __forceinline__ uint32_t pack2(float a, float b) {
    uint32_t ua = __float_as_uint(a), ub = __float_as_uint(b);
    ua = (ua + 0x7FFFu + ((ua >> 16) & 1u)) >> 16;
    ub = (ub + 0x7FFFu + ((ub >> 16) & 1u)) & 0xFFFF0000u;
    return ua | ub;
}
__device__ __forceinline__ float4 unpack4(uint32_t a, uint32_t b) {
    float4 v;
    v.x = __uint_as_float(a << 16);
    v.y = __uint_as_float(a & 0xFFFF0000u);
    v.z = __uint_as_float(b << 16);
    v.w = __uint_as_float(b & 0xFFFF0000u);
    return v;
}
// sum across the 16 lanes of this row-group; pure VALU (DPP row_ror tree)
__device__ __forceinline__ float row16_sum(float d) {
    d += __int_as_float(__builtin_amdgcn_update_dpp(0, __float_as_int(d), 0x128, 0xF, 0xF, true));
    d += __int_as_float(__builtin_amdgcn_update_dpp(0, __float_as_int(d), 0x124, 0xF, 0xF, true));
    d += __int_as_float(__builtin_amdgcn_update_dpp(0, __float_as_int(d), 0x122, 0xF, 0xF, true));
    d += __int_as_float(__builtin_amdgcn_update_dpp(0, __float_as_int(d), 0x121, 0xF, 0xF, true));
    return d;
}
__device__ __forceinline__ float dot8(float4 lo, float4 hi, float4 clo, float4 chi) {
    float a = lo.x * clo.x + lo.y * clo.y;
    float b = lo.z * clo.z + lo.w * clo.w;
    float c = hi.x * chi.x + hi.y * chi.y;
    float d = hi.z * chi.z + hi.w * chi.w;
    return (a + b) + (c + d);
}

extern "C" __global__ __launch_bounds__(BLK)
__attribute__((amdgpu_waves_per_eu(2, 2)))   // PIN 2 waves/EU: 256-VGPR budget, no occupancy-chasing spill
void cba_pipe_reg_kernel(const float* __restrict__ x,
                         const float* __restrict__ W,
                         const int* __restrict__ batch,
                         float* __restrict__ out,
                         int N, int B, int totalWaves)
{
    // W as bf16 pairs, padded rows; rows rotated per k-quarter to spread banks.
    __shared__ uint32_t sWb[C * WSTRIDE];   // 34816 B
    __shared__ float4   sMean[WPB * 32];    // 2048 B : per-wave mean broadcast

    const int t    = threadIdx.x;
    const int lane = t & 63;
    const int wid  = t >> 6;       // wave in block 0..3
    const int rg   = lane >> 4;    // row-group / split-K quarter 0..3
    const int c16  = lane & 15;    // owns channels c16*8 .. c16*8+7

    // ---- one-time: W -> bf16 -> LDS (padded + per-quarter rotation) ----
    const float2* W2 = (const float2*)W;
    for (int p = t; p < C * 64; p += BLK) {
        const int k = p >> 6, j = p & 63;
        const float2 wv = W2[p];
        sWb[k * WSTRIDE + ((j + ((k >> 5) << 3)) & 63)] = pack2(wv.x, wv.y);
    }
    __syncthreads();

    const int gw = blockIdx.x * WPB + wid;

    // ---- chunk-contiguous segment assignment ----
    const int qn = B / totalWaves;
    const int r  = B % totalWaves;
    const int segStart = gw * qn + (gw < r ? gw : r);
    const int myCnt    = qn + (gw < r ? 1 : 0);       // <= 25

    // ---- lane-parallel boundary search: lane l -> start of segment segStart+min(l,myCnt) ----
    const int tl     = lane < myCnt ? lane : myCnt;
    const int target = segStart + tl;
    int lo_ = 0, hi_ = N;
    while (lo_ < hi_) {
        int mid = (lo_ + hi_) >> 1;
        if (batch[mid] < target) lo_ = mid + 1; else hi_ = mid;
    }
    const int bs = lo_;

    const float4* x4  = (const float4*)x;
    const int     Nm1 = N - 1;
    float4* mb = sMean + wid * 32;
    // constant per-lane rotated column offset into a W row
    const int co = (((c16 << 2) + (rg << 3)) & 63);

    // prefetch window: next segment's rows, fp32 (96 VGPR)
    float4 pl[MAXSLOT], ph[MAXSLOT];

#define ISSUE(sseg)                                                    \
    {                                                                  \
        _Pragma("unroll")                                              \
        for (int sl = 0; sl < MAXSLOT; ++sl) {                         \
            const int row = (sseg) + 4 * sl + rg;                      \
            const int rc  = row < Nm1 ? row : Nm1;                     \
            pl[sl] = x4[(size_t)rc * 32 + (c16 << 1)];                 \
            ph[sl] = x4[(size_t)rc * 32 + (c16 << 1) + 1];             \
        }                                                              \
    }

    int sCur = 0, eCur = 0;
    if (myCnt > 0) {
        sCur = __shfl(bs, 0, 64);
        eCur = __shfl(bs, 1, 64);
        ISSUE(sCur);                                   // prologue: segment 0 in flight
    }

    for (int k = 0; k < myCnt; ++k) {
        const int b   = segStart + k;
        const int s   = sCur;
        const int e   = eCur;
        const int cnt = e - s;

        // ======== consume prefetched rows: mask, fp32 sum, bf16-pack to regs ========
        uint4 rbPk[MAXSLOT];                           // 48 VGPR: current segment, bf16
        float4 alo = make_float4(0.f,0.f,0.f,0.f), ahi = alo;
#pragma unroll
        for (int sl = 0; sl < MAXSLOT; ++sl) {
            const int  row   = s + 4 * sl + rg;
            const bool valid = row < e;
            float4 lo = pl[sl], hi = ph[sl];
            lo.x = valid ? lo.x : 0.f; lo.y = valid ? lo.y : 0.f;
            lo.z = valid ? lo.z : 0.f; lo.w = valid ? lo.w : 0.f;
            hi.x = valid ? hi.x : 0.f; hi.y = valid ? hi.y : 0.f;
            hi.z = valid ? hi.z : 0.f; hi.w = valid ? hi.w : 0.f;
            alo = f4add(alo, lo); ahi = f4add(ahi, hi);
            rbPk[sl].x = pack2(lo.x, lo.y); rbPk[sl].y = pack2(lo.z, lo.w);
            rbPk[sl].z = pack2(hi.x, hi.y); rbPk[sl].w = pack2(hi.z, hi.w);
        }
        // rare tail rows > 48: sum synchronously (L2-hot for pass-2 re-read)
        for (int i = s + NROW + rg; i < e; i += 4) {
            alo = f4add(alo, x4[(size_t)i * 32 + (c16 << 1)]);
            ahi = f4add(ahi, x4[(size_t)i * 32 + (c16 << 1) + 1]);
        }

        // ======== issue prefetch for segment k+1 NOW; flies under GEMM + pass 2 ========
        if (k + 1 < myCnt) {
            sCur = __shfl(bs, k + 1, 64);
            eCur = __shfl(bs, k + 2, 64);
            ISSUE(sCur);
        }
        __builtin_amdgcn_sched_barrier(0);             // don't let the loads sink below

        // ======== mean (cross-row-group reduce) ========
        alo = f4add(alo, f4shfl_xor(alo, 16));
        alo = f4add(alo, f4shfl_xor(alo, 32));
        ahi = f4add(ahi, f4shfl_xor(ahi, 16));
        ahi = f4add(ahi, f4shfl_xor(ahi, 32));
        const float inv = 1.0f / (float)(cnt > 0 ? cnt : 1);
        if (lane < 16) {
            float4 mlo, mhi;
            mlo.x = alo.x*inv; mlo.y = alo.y*inv; mlo.z = alo.z*inv; mlo.w = alo.w*inv;
            mhi.x = ahi.x*inv; mhi.y = ahi.y*inv; mhi.z = ahi.z*inv; mhi.w = ahi.w*inv;
            mb[2 * c16]     = mlo;
            mb[2 * c16 + 1] = mhi;
        }
        // same-wave ds_write -> ds_read; compiler inserts lgkmcnt

        // ======== GEMM: c = tanh(mean @ W); quarter rg covers k in [32rg, 32rg+32) ========
        float4 plo = make_float4(0.f,0.f,0.f,0.f), phi = plo;
#pragma unroll
        for (int jq = 0; jq < 8; ++jq) {
            const float4 m4 = mb[(rg << 3) + jq];
            const int kb = (rg << 5) + (jq << 2);
            const uint4 u0 = *(const uint4*)&sWb[(kb + 0) * WSTRIDE + co];
            const uint4 u1 = *(const uint4*)&sWb[(kb + 1) * WSTRIDE + co];
            const uint4 u2 = *(const uint4*)&sWb[(kb + 2) * WSTRIDE + co];
            const uint4 u3 = *(const uint4*)&sWb[(kb + 3) * WSTRIDE + co];
#define FMA8(mm, uu)                                                          \
            {                                                                 \
                plo.x = fmaf(mm, __uint_as_float((uu).x << 16),        plo.x);\
                plo.y = fmaf(mm, __uint_as_float((uu).x & 0xFFFF0000u),plo.y);\
                plo.z = fmaf(mm, __uint_as_float((uu).y << 16),        plo.z);\
                plo.w = fmaf(mm, __uint_as_float((uu).y & 0xFFFF0000u),plo.w);\
                phi.x = fmaf(mm, __uint_as_float((uu).z << 16),        phi.x);\
                phi.y = fmaf(mm, __uint_as_float((uu).z & 0xFFFF0000u),phi.y);\
                phi.z = fmaf(mm, __uint_as_float((uu).w << 16),        phi.z);\
                phi.w = fmaf(mm, __uint_as_float((uu).w & 0xFFFF0000u),phi.w);\
            }
            FMA8(m4.x, u0); FMA8(m4.y, u1); FMA8(m4.z, u2); FMA8(m4.w, u3);
#undef FMA8
        }
        plo = f4add(plo, f4shfl_xor(plo, 16));
        plo = f4add(plo, f4shfl_xor(plo, 32));
        phi = f4add(phi, f4shfl_xor(phi, 16));
        phi = f4add(phi, f4shfl_xor(phi, 32));
        float4 clo, chi;
        clo.x = fast_tanh(plo.x); clo.y = fast_tanh(plo.y);
        clo.z = fast_tanh(plo.z); clo.w = fast_tanh(plo.w);
        chi.x = fast_tanh(phi.x); chi.y = fast_tanh(phi.y);
        chi.z = fast_tanh(phi.z); chi.w = fast_tanh(phi.w);

        // ======== pass 2: gates + h from bf16 regs; DPP-only row reduction ========
        float4 hlo = make_float4(0.f,0.f,0.f,0.f), hhi = hlo;
#pragma unroll
        for (int sl = 0; sl < MAXSLOT; ++sl) {
            const float4 lo = unpack4(rbPk[sl].x, rbPk[sl].y);
            const float4 hi = unpack4(rbPk[sl].z, rbPk[sl].w);
            float d = dot8(lo, hi, clo, chi);
            d = row16_sum(d);
            const float g = fast_sigmoid(d);           // masked rows staged as 0 -> g*0
            hlo.x = fmaf(g, lo.x, hlo.x); hlo.y = fmaf(g, lo.y, hlo.y);
            hlo.z = fmaf(g, lo.z, hlo.z); hlo.w = fmaf(g, lo.w, hlo.w);
            hhi.x = fmaf(g, hi.x, hhi.x); hhi.y = fmaf(g, hi.y, hhi.y);
            hhi.z = fmaf(g, hi.z, hhi.z); hhi.w = fmaf(g, hi.w, hhi.w);
        }
        // tail rows > 48: re-read from global (L2-hot)
        for (int i = s + NROW + rg; i < e; i += 4) {
            const float4 lo = x4[(size_t)i * 32 + (c16 << 1)];
            const float4 hi = x4[(size_t)i * 32 + (c16 << 1) + 1];
            float d = dot8(lo, hi, clo, chi);
            d = row16_sum(d);
            const float g = fast_sigmoid(d);
            hlo.x = fmaf(g, lo.x, hlo.x); hlo.y = fmaf(g, lo.y, hlo.y);
            hlo.z = fmaf(g, lo.z, hlo.z); hlo.w = fmaf(g, lo.w, hlo.w);
            hhi.x = fmaf(g, hi.x, hhi.x); hhi.y = fmaf(g, hi.y, hhi.y);
            hhi.z = fmaf(g, hi.z, hhi.z); hhi.w = fmaf(g, hi.w, hhi.w);
        }
        hlo = f4add(hlo, f4shfl_xor(hlo, 16));
        hlo = f4add(hlo, f4shfl_xor(hlo, 32));
        hhi = f4add(hhi, f4shfl_xor(hhi, 16));
        hhi = f4add(hhi, f4shfl_xor(hhi, 32));
        if (lane < 16) {
            ((float4*)out)[(size_t)b * 32 + (c16 << 1)]     = hlo;
            ((float4*)out)[(size_t)b * 32 + (c16 << 1) + 1] = hhi;
        }
    }
#undef ISSUE
}

extern "C" void kernel_launch(void* const* d_in, const int* in_sizes, int n_in,
                              void* d_out, int out_size, void* d_ws, size_t ws_size,
                              hipStream_t stream) {
    const float* x     = (const float*)d_in[0];
    const float* W     = (const float*)d_in[1];
    const int*   batch = (const int*)d_in[2];
    float*       out   = (float*)d_out;

    const int N = in_sizes[0] / C;   // 2,000,000
    const int B = out_size / C;      // 50,000

    const int grid       = 512;                 // 2 blocks/CU (37 KB LDS), 8 waves/CU
    const int totalWaves = grid * WPB;          // 2048 waves, ~24 contiguous segments each
    hipLaunchKernelGGL(cba_pipe_reg_kernel, dim3(grid), dim3(BLK), 0, stream,
                       x, W, batch, out, N, B, totalWaves);
}